// Round 3
// baseline (37.760 us; speedup 1.0000x reference)
//
#include <hip/hip_runtime.h>

#define GRIDS 7
#define NCELL 49
#define NFEAT 25
#define CELLSZ 1225   // 49*25 floats per batch
#define BPB 4         // batches per block: 4*1225*4B = 19600 B, float4-aligned
#define MAXBOX 16

// sPair[e] = (tgt, wgt) per element e in the block's slab.
//   wgt sign bit => compare against sqrt(p) instead of p.
//   f in [0,2): tgt=xo|yo          wgt=+5*obj
//   f in [2,4): tgt=sqrt(w|h)      wgt=-5*obj   (-0.0 when obj=0: w<0 false, weight 0)
//   f == 4   : tgt=obj             wgt=0.5+0.5*obj
//   f >= 5   : tgt=onehot          wgt=obj
__device__ __forceinline__ float term(float p, float t, float w) {
    float q = (w < 0.f) ? sqrtf(p) : p;
    float d = t - q;
    return fabsf(w) * d * d;   // abs folds to VOP3 input modifier
}

__global__ __launch_bounds__(256, 4) void yolo_main(
    const float* __restrict__ pred, const float* __restrict__ bbox,
    float* __restrict__ partial, int B, int nbox)
{
    __shared__ float2 sPair[BPB * CELLSZ];          // 39200 B
    __shared__ float  sBox[BPB * MAXBOX * 5];       // 1280 B
    __shared__ int    sCellIdx[BPB * MAXBOX];       // 256 B
    __shared__ float  sRed[4];

    const int tid = threadIdx.x;
    const long long b0 = (long long)blockIdx.x * BPB;
    const int nb = min(BPB, B - (int)b0);
    const int nelem = nb * CELLSZ;

    // Phase 0: per-box derived values (<=64 boxes, one thread each)
    if (tid < nb * nbox) {
        const float* bx = bbox + (b0 * nbox + tid) * 5;
        float x1 = bx[0] / 448.f, y1 = bx[1] / 448.f;
        float x2 = bx[2] / 448.f, y2 = bx[3] / 448.f;
        float xc = (x1 + x2) * 0.5f, yc = (y1 + y2) * 0.5f;
        float w  = x2 - x1,          h  = y2 - y1;
        float xs = xc * (float)GRIDS, ys = yc * (float)GRIDS;
        float xgf = floorf(xs), ygf = floorf(ys);
        sCellIdx[tid] = (int)ygf * GRIDS + (int)xgf;
        float* e = &sBox[tid * 5];
        e[0] = xs - xgf; e[1] = ys - ygf;
        e[2] = sqrtf(w); e[3] = sqrtf(h);
        e[4] = bx[4];
    }

    // Phase 1: default (noobj) pattern for every element
    for (int t = tid; t < nelem; t += 256) {
        unsigned c25 = ((unsigned)t * 5243u) >> 17;    // t/25, exact for t<4900
        unsigned f   = (unsigned)t - c25 * 25u;
        float w = 0.f;
        if (f == 4u) w = 0.5f;
        else if (f == 2u || f == 3u) w = -0.f;         // sqrt flag, zero weight
        sPair[t] = make_float2(0.f, w);
    }
    __syncthreads();

    // Phase 2: obj cells overwrite their 25 pairs (first box in cell wins)
    for (int t = tid; t < nb * NCELL; t += 256) {
        unsigned lb = ((unsigned)t * 2676u) >> 17;     // t/49, exact for t<196
        int c = t - (int)lb * NCELL;
        int hit = -1;
        for (int j = 0; j < nbox; ++j) {
            if (sCellIdx[lb * nbox + j] == c) { hit = j; break; }
        }
        if (hit >= 0) {
            const float* e = &sBox[(lb * nbox + hit) * 5];
            int lab = (int)e[4];
            float2* o = &sPair[t * NFEAT];              // lb*1225 + c*25 == t*25
            o[0] = make_float2(e[0],  5.f);
            o[1] = make_float2(e[1],  5.f);
            o[2] = make_float2(e[2], -5.f);
            o[3] = make_float2(e[3], -5.f);
            o[4] = make_float2(1.f,   1.f);
            #pragma unroll
            for (int k = 0; k < 20; ++k)
                o[5 + k] = make_float2(k == lab ? 1.f : 0.f, 1.f);
        }
    }
    __syncthreads();

    // Main loop: stream float4 pred, look up pairs flat, 2 loads in flight
    const int nvec = nelem >> 2;                       // 1225 for full blocks
    const float*  pb = pred + b0 * CELLSZ;
    const float4* p4 = (const float4*)pb;
    const float4* t4 = (const float4*)sPair;           // 2 pairs per float4
    float acc = 0.f;
    int i = tid;
    for (; i + 256 < nvec; i += 512) {
        float4 a = p4[i];
        float4 b = p4[i + 256];
        float4 qa0 = t4[2 * i],       qa1 = t4[2 * i + 1];
        float4 qb0 = t4[2 * i + 512], qb1 = t4[2 * i + 513];
        acc += term(a.x, qa0.x, qa0.y);
        acc += term(a.y, qa0.z, qa0.w);
        acc += term(a.z, qa1.x, qa1.y);
        acc += term(a.w, qa1.z, qa1.w);
        acc += term(b.x, qb0.x, qb0.y);
        acc += term(b.y, qb0.z, qb0.w);
        acc += term(b.z, qb1.x, qb1.y);
        acc += term(b.w, qb1.z, qb1.w);
    }
    if (i < nvec) {
        float4 a = p4[i];
        float4 q0 = t4[2 * i], q1 = t4[2 * i + 1];
        acc += term(a.x, q0.x, q0.y);
        acc += term(a.y, q0.z, q0.w);
        acc += term(a.z, q1.x, q1.y);
        acc += term(a.w, q1.z, q1.w);
    }
    // scalar tail (partial last block only)
    for (int e = (nvec << 2) + tid; e < nelem; e += 256) {
        float2 q = sPair[e];
        acc += term(pb[e], q.x, q.y);
    }

    // Deterministic block reduction
    for (int off = 32; off; off >>= 1)
        acc += __shfl_down(acc, off, 64);
    if ((tid & 63) == 0) sRed[tid >> 6] = acc;
    __syncthreads();
    if (tid == 0)
        partial[blockIdx.x] = sRed[0] + sRed[1] + sRed[2] + sRed[3];
}

__global__ __launch_bounds__(256) void yolo_reduce(
    const float* __restrict__ partial, int n, float* __restrict__ out, int B)
{
    __shared__ double s[256];
    double a = 0.0;
    for (int i = threadIdx.x; i < n; i += 256) a += (double)partial[i];
    s[threadIdx.x] = a;
    __syncthreads();
    for (int str = 128; str; str >>= 1) {
        if (threadIdx.x < str) s[threadIdx.x] += s[threadIdx.x + str];
        __syncthreads();
    }
    if (threadIdx.x == 0) out[0] = (float)(s[0] / (double)B);
}

extern "C" void kernel_launch(void* const* d_in, const int* in_sizes, int n_in,
                              void* d_out, int out_size, void* d_ws, size_t ws_size,
                              hipStream_t stream) {
    const float* pred = (const float*)d_in[0];
    const float* bbox = (const float*)d_in[1];
    int B = in_sizes[0] / CELLSZ;
    int nbox = in_sizes[1] / (B * 5);
    if (nbox > MAXBOX) nbox = MAXBOX;
    float* out = (float*)d_out;
    float* partial = (float*)d_ws;

    int nblocks = (B + BPB - 1) / BPB;
    yolo_main<<<nblocks, 256, 0, stream>>>(pred, bbox, partial, B, nbox);
    yolo_reduce<<<1, 256, 0, stream>>>(partial, nblocks, out, B);
}

// Round 4
// 26.789 us; speedup vs baseline: 1.4096x; 1.4096x over previous
//
#include <hip/hip_runtime.h>

#define GRIDS 7
#define NCELL 49
#define NFEAT 25
#define CELLSZ 1225   // 49*25 floats per batch
#define BPB 8         // batches per block: 8*1225*4B = 39200 B, float4-aligned
#define MAXBOX 16

// Decomposition:
//   stream:   every cell contributes 0.5 * p_conf^2   (the noobj default)
//   correct:  each kept box's cell adds
//     f<2 : 5*(xo|yo - p)^2
//     f=2,3: 5*(sqrt(w|h) - sqrt(p))^2
//     f=4 : (1-p)^2 - 0.5*p^2     (replace default with obj conf term)
//     f>=5: (onehot - p)^2

__global__ __launch_bounds__(256) void yolo_main(
    const float* __restrict__ pred, const float* __restrict__ bbox,
    float* __restrict__ partial, int B, int nbox)
{
    __shared__ float sBox[BPB * MAXBOX * 5];   // xo, yo, sqrt(w), sqrt(h), label
    __shared__ int   sCell[BPB * MAXBOX];
    __shared__ int   sKeep[BPB * MAXBOX];
    __shared__ float sRed[4];

    const int tid = threadIdx.x;
    const long long b0 = (long long)blockIdx.x * BPB;
    const int nb = min(BPB, B - (int)b0);
    const int nbx = nb * nbox;                  // <= 256

    // Preamble A: per-box derived values (f32 op order matches reference)
    if (tid < nbx) {
        const float* bx = bbox + (b0 * nbox + tid) * 5;
        float x1 = bx[0] / 448.f, y1 = bx[1] / 448.f;
        float x2 = bx[2] / 448.f, y2 = bx[3] / 448.f;
        float xc = (x1 + x2) * 0.5f, yc = (y1 + y2) * 0.5f;
        float w  = x2 - x1,          h  = y2 - y1;
        float xs = xc * (float)GRIDS, ys = yc * (float)GRIDS;
        float xg = floorf(xs), yg = floorf(ys);
        sCell[tid] = (int)yg * GRIDS + (int)xg;
        float* e = &sBox[tid * 5];
        e[0] = xs - xg; e[1] = ys - yg;
        e[2] = sqrtf(w); e[3] = sqrtf(h);
        e[4] = bx[4];
    }
    __syncthreads();

    // Preamble B: keep mask — first box claiming a cell wins
    if (tid < nbx) {
        int lb = tid / nbox;
        int c  = sCell[tid];
        int k = 1;
        for (int i = lb * nbox; i < tid; ++i)
            if (sCell[i] == c) { k = 0; break; }
        sKeep[tid] = k;
    }
    __syncthreads();

    // Streaming pass: 0.5*p^2 for the conf lane of each float4 group.
    // Element e=4i+k is conf iff (e mod 25)==4, i.e. r=(4i mod 25) in {4,3,2,1}.
    const int nelem = nb * CELLSZ;
    const int nvec  = nelem >> 2;               // 2450 for full blocks
    const float* pb = pred + b0 * CELLSZ;
    const float4* p4 = (const float4*)pb;
    float acc = 0.f;
    int i = tid;
    for (; i + 256 < nvec; i += 512) {
        float4 a = p4[i];
        float4 b = p4[i + 256];
        {
            unsigned e0 = (unsigned)i << 2;
            unsigned q = (e0 * 5243u) >> 17;    // e0/25, exact for e0 < 43690
            unsigned r = e0 - q * 25u;
            float c = (r == 4u) ? a.x : (r == 3u) ? a.y : (r == 2u) ? a.z
                    : (r == 1u) ? a.w : 0.f;
            acc = fmaf(0.5f * c, c, acc);
        }
        {
            unsigned e0 = (unsigned)(i + 256) << 2;
            unsigned q = (e0 * 5243u) >> 17;
            unsigned r = e0 - q * 25u;
            float c = (r == 4u) ? b.x : (r == 3u) ? b.y : (r == 2u) ? b.z
                    : (r == 1u) ? b.w : 0.f;
            acc = fmaf(0.5f * c, c, acc);
        }
    }
    if (i < nvec) {
        float4 a = p4[i];
        unsigned e0 = (unsigned)i << 2;
        unsigned q = (e0 * 5243u) >> 17;
        unsigned r = e0 - q * 25u;
        float c = (r == 4u) ? a.x : (r == 3u) ? a.y : (r == 2u) ? a.z
                : (r == 1u) ? a.w : 0.f;
        acc = fmaf(0.5f * c, c, acc);
    }
    // scalar tail (only for a partial last block)
    for (int e = (nvec << 2) + tid; e < nelem; e += 256) {
        unsigned q = ((unsigned)e * 5243u) >> 17;
        if ((unsigned)e - q * 25u == 4u) {
            float p = pb[e];
            acc = fmaf(0.5f * p, p, acc);
        }
    }

    // Correction pass: kept boxes' cells, one (box,feature) item per thread.
    // Reads are L1/L2-hot (this block just streamed them).
    for (int t = tid; t < nbx * NFEAT; t += 256) {
        unsigned bi = ((unsigned)t * 5243u) >> 17;   // t/25
        int f = t - (int)bi * NFEAT;
        if (sKeep[bi]) {
            int lb = (int)bi / nbox;
            const float* e = &sBox[bi * 5];
            float p = pb[lb * CELLSZ + sCell[bi] * NFEAT + f];
            float term;
            if (f < 2) {
                float d = e[f] - p;           term = 5.f * d * d;
            } else if (f < 4) {
                float d = e[f] - sqrtf(p);    term = 5.f * d * d;
            } else if (f == 4) {
                float d = 1.f - p;            term = d * d - 0.5f * p * p;
            } else {
                float tt = ((int)e[4] == f - 5) ? 1.f : 0.f;
                float d = tt - p;             term = d * d;
            }
            acc += term;
        }
    }

    // Deterministic block reduction
    for (int off = 32; off; off >>= 1)
        acc += __shfl_down(acc, off, 64);
    if ((tid & 63) == 0) sRed[tid >> 6] = acc;
    __syncthreads();
    if (tid == 0)
        partial[blockIdx.x] = sRed[0] + sRed[1] + sRed[2] + sRed[3];
}

__global__ __launch_bounds__(256) void yolo_reduce(
    const float* __restrict__ partial, int n, float* __restrict__ out, int B)
{
    __shared__ double s[256];
    double a = 0.0;
    for (int i = threadIdx.x; i < n; i += 256) a += (double)partial[i];
    s[threadIdx.x] = a;
    __syncthreads();
    for (int str = 128; str; str >>= 1) {
        if (threadIdx.x < str) s[threadIdx.x] += s[threadIdx.x + str];
        __syncthreads();
    }
    if (threadIdx.x == 0) out[0] = (float)(s[0] / (double)B);
}

extern "C" void kernel_launch(void* const* d_in, const int* in_sizes, int n_in,
                              void* d_out, int out_size, void* d_ws, size_t ws_size,
                              hipStream_t stream) {
    const float* pred = (const float*)d_in[0];
    const float* bbox = (const float*)d_in[1];
    int B = in_sizes[0] / CELLSZ;
    int nbox = in_sizes[1] / (B * 5);
    if (nbox > MAXBOX) nbox = MAXBOX;
    float* out = (float*)d_out;
    float* partial = (float*)d_ws;

    int nblocks = (B + BPB - 1) / BPB;
    yolo_main<<<nblocks, 256, 0, stream>>>(pred, bbox, partial, B, nbox);
    yolo_reduce<<<1, 256, 0, stream>>>(partial, nblocks, out, B);
}